// Round 8
// baseline (2343.314 us; speedup 1.0000x reference)
//
#include <hip/hip_runtime.h>

#define H 1024
#define I_DIM 128
#define O_DIM 128
#define T_DIM 512
#define ALPHA 0.2f
#define NWG 64          // 4 batch-groups x 16 j-slices
#define GSZ 16          // WGs per batch-group

typedef short short8 __attribute__((ext_vector_type(8)));
typedef float f32x4 __attribute__((ext_vector_type(4)));
typedef unsigned long long ull_alias __attribute__((may_alias));

__device__ __forceinline__ unsigned short f2b(float f) {
    union { float f; unsigned u; } x; x.f = f;
    unsigned u = x.u;
    return (unsigned short)((u + 0x7FFFu + ((u >> 16) & 1u)) >> 16);
}
__device__ __forceinline__ float tanh_fast(float x) {
    float e = __expf(2.0f * x);
    return 1.0f - 2.0f * __builtin_amdgcn_rcpf(e + 1.0f);
}
// 8 contiguous f32 -> bf16 fragment (RNE)
__device__ __forceinline__ short8 ld8f(const float* __restrict__ p) {
    const float4 a = *(const float4*)p;
    const float4 b = *(const float4*)(p + 4);
    short8 r;
    r[0]=(short)f2b(a.x); r[1]=(short)f2b(a.y); r[2]=(short)f2b(a.z); r[3]=(short)f2b(a.w);
    r[4]=(short)f2b(b.x); r[5]=(short)f2b(b.y); r[6]=(short)f2b(b.z); r[7]=(short)f2b(b.w);
    return r;
}

// Embedded-tag protocol: each logical 8 B of packed-A data (4 bf16) is published
// as a PAIR of self-verifying 8 B slots:
//   slot0 = d0 | d1<<16 | d2<<32 | tag<<48
//   slot1 = d3 |       ...       | tag<<48      (tag = step & 0xFFFF)
// Stored with relaxed agent-scope atomics (LLC-coherent). Consumers load
// speculatively and retry slots whose tag != expected step. No tag array, no
// vmcnt drains, no acquire/release, no cache maintenance anywhere.
// WAR safety on the 2-parity ring (no drain needed): producer P issues t+2
// stores only after validating all waves' t+1 data; any wave published t+1 only
// after fully consuming t; consuming t required P's t-stores to have ARRIVED at
// the LLC. Hence P's t-stores are globally visible before its t+2 stores are
// issued -> no same-address race, and no consumer can still want parity-slot
// data that gets overwritten.
// Pair index for (ji, w, lane): u = ji*256 + w*64 + lane; address = base + u*2
// (u64 units). Consumer wave cw, unit i in [0,16), lane: u = cw*1024 + i*64 + lane,
// which also equals its ds_write target index in abuf (u64 view).
__global__ __launch_bounds__(256, 1) void rnn_kernel(
    const float* __restrict__ x, const float* __restrict__ wi,
    const float* __restrict__ wrec, const float* __restrict__ wout,
    const float* __restrict__ bb, const float* __restrict__ gg,
    const float* __restrict__ h0p, float* __restrict__ out,
    unsigned long long* __restrict__ aG)
{
    __shared__ unsigned short abuf[32 * 512];   // 32 KB: group's full a_{t-1}
    __shared__ unsigned short aloc[1024];       // 2 KB: own a_t slice, packed
    __shared__ float opart[4 * 128];            // 2 KB: out k-partials

    const int tid  = threadIdx.x;
    const int w    = tid >> 6, lane = tid & 63;
    const int n    = lane & 15, q = lane >> 4;
    const int grp  = blockIdx.x & 3;
    const int ji   = blockIdx.x >> 2;
    const int j0   = ji * 64;
    const int j    = j0 + w * 16 + n;           // this lane's owned h row
    const int b0   = grp * 16;

    // ---- register-resident weights (f32 -> bf16, once) ----
    short8 wfr[32];                              // wrec B-frags: B[k][j] = wrec[j][k]
#pragma unroll
    for (int kt = 0; kt < 32; ++kt)
        wfr[kt] = ld8f(&wrec[(size_t)j * H + kt * 32 + q * 8]);

    short8 wifr[4];                              // wi B-frags: B[k][j] = wi[k][j]
#pragma unroll
    for (int kt = 0; kt < 4; ++kt) {
        short8 v;
#pragma unroll
        for (int i = 0; i < 8; ++i)
            v[i] = (short)f2b(wi[(size_t)(kt * 32 + q * 8 + i) * H + j]);
        wifr[kt] = v;
    }
    short8 wofr[8];                              // wout B-frags, cols ji*8..+8, zero-pad n>=8
#pragma unroll
    for (int kk = 0; kk < 8; ++kk) {
        short8 v;
        const int kb = (w * 8 + kk) * 32 + q * 8;
#pragma unroll
        for (int i = 0; i < 8; ++i)
            v[i] = (n < 8) ? (short)f2b(wout[(size_t)(kb + i) * O_DIM + ji * 8 + n]) : (short)0;
        wofr[kk] = v;
    }

    const float gv = gg[j], bv = bb[j], h00 = h0p[j];
    float hreg[4];
#pragma unroll
    for (int r = 0; r < 4; ++r) hreg[r] = h00;

    const int kl    = w * 16 + n;                // local k in [0,64)
    const int off_l = (kl >> 5) * 512 + ((kl & 31) >> 3) * 128 + (kl & 7);
    const int upub  = ji * 256 + w * 64 + lane;  // this lane's pair index

    // publish: read own 8 B from aloc, split into 2 tagged slots, fire & forget
    auto publish = [&](int t) {
        asm volatile("" ::: "memory");
        unsigned long long v = *(const ull_alias*)&aloc[w * 256 + lane * 4];
        const unsigned long long tg = (unsigned long long)(t & 0xFFFF) << 48;
        unsigned long long s0 = (v & 0x0000FFFFFFFFFFFFull) | tg;
        unsigned long long s1 = ((v >> 48) & 0xFFFFull) | tg;
        unsigned long long* dst =
            aG + (size_t)((t & 1) * 4 + grp) * 8192 + (size_t)upub * 2;
        __hip_atomic_store(dst + 0, s0, __ATOMIC_RELAXED, __HIP_MEMORY_SCOPE_AGENT);
        __hip_atomic_store(dst + 1, s1, __ATOMIC_RELAXED, __HIP_MEMORY_SCOPE_AGENT);
    };

    // consume: speculative loads, validate embedded tags, retry stale slots,
    // then ds_write into abuf. Chunks of 4 units keep VGPR pressure at R7 level.
    auto consume = [&](int tv) {
        const unsigned long long want = (unsigned long long)(tv & 0xFFFF);
        const unsigned long long* src = aG + (size_t)((tv & 1) * 4 + grp) * 8192;
        ull_alias* d64 = (ull_alias*)abuf;
#pragma unroll
        for (int c = 0; c < 4; ++c) {
            unsigned long long s0[4], s1[4];
#pragma unroll
            for (int i = 0; i < 4; ++i) {
                const unsigned long long* p =
                    src + (size_t)(w * 1024 + (c * 4 + i) * 64 + lane) * 2;
                s0[i] = __hip_atomic_load(p + 0, __ATOMIC_RELAXED, __HIP_MEMORY_SCOPE_AGENT);
                s1[i] = __hip_atomic_load(p + 1, __ATOMIC_RELAXED, __HIP_MEMORY_SCOPE_AGENT);
            }
            for (;;) {
                unsigned bad = 0;
#pragma unroll
                for (int i = 0; i < 4; ++i)
                    if (((s0[i] >> 48) != want) || ((s1[i] >> 48) != want)) bad |= 1u << i;
                if (__all(bad == 0)) break;
#pragma unroll
                for (int i = 0; i < 4; ++i)
                    if (bad & (1u << i)) {
                        const unsigned long long* p =
                            src + (size_t)(w * 1024 + (c * 4 + i) * 64 + lane) * 2;
                        s0[i] = __hip_atomic_load(p + 0, __ATOMIC_RELAXED, __HIP_MEMORY_SCOPE_AGENT);
                        s1[i] = __hip_atomic_load(p + 1, __ATOMIC_RELAXED, __HIP_MEMORY_SCOPE_AGENT);
                    }
            }
            asm volatile("" ::: "memory");
#pragma unroll
            for (int i = 0; i < 4; ++i) {
                unsigned long long v = (s0[i] & 0x0000FFFFFFFFFFFFull) |
                                       ((s1[i] & 0xFFFFull) << 48);
                d64[(size_t)w * 1024 + (c * 4 + i) * 64 + lane] = v;
            }
        }
    };

    // out[:, t, ji*8..+8) from abuf (full k=1024 chain)
    auto do_out = [&](int t) {
        f32x4 oa = {0.f, 0.f, 0.f, 0.f};
#pragma unroll
        for (int kk = 0; kk < 8; ++kk) {
            short8 af = *(const short8*)&abuf[(w * 8 + kk) * 512 + lane * 8];
            oa = __builtin_amdgcn_mfma_f32_16x16x32_bf16(af, wofr[kk], oa, 0, 0, 0);
        }
        if (n < 8) {
#pragma unroll
            for (int r = 0; r < 4; ++r) opart[w * 128 + (4 * q + r) * 8 + n] = oa[r];
        }
        __syncthreads();
        if (tid < 128) {
            float s = opart[tid] + opart[128 + tid] + opart[256 + tid] + opart[384 + tid];
            const int m = tid >> 3, c = tid & 7;
            out[((size_t)(b0 + m) * T_DIM + t) * O_DIM + ji * 8 + c] = s;
        }
    };

    // ---- init: stage + publish a0 = g*tanh(h0+b) (batch-broadcast) ----
    {
        unsigned short a0 = f2b(gv * tanh_fast(h00 + bv));
#pragma unroll
        for (int r = 0; r < 4; ++r) aloc[off_l + (4 * q + r) * 8] = a0;
        publish(0);
    }

    short8 xfr[4];                               // prefetch x[:,0,:]
#pragma unroll
    for (int kt = 0; kt < 4; ++kt)
        xfr[kt] = ld8f(&x[(size_t)(b0 + n) * T_DIM * I_DIM + kt * 32 + q * 8]);

    for (int t = 1; t < T_DIM; ++t) {
        // x@wi partials: register-only, overlaps stragglers
        f32x4 acc0 = {0.f,0.f,0.f,0.f}, acc1 = {0.f,0.f,0.f,0.f};
        acc0 = __builtin_amdgcn_mfma_f32_16x16x32_bf16(xfr[0], wifr[0], acc0, 0,0,0);
        acc1 = __builtin_amdgcn_mfma_f32_16x16x32_bf16(xfr[1], wifr[1], acc1, 0,0,0);
        acc0 = __builtin_amdgcn_mfma_f32_16x16x32_bf16(xfr[2], wifr[2], acc0, 0,0,0);
        acc1 = __builtin_amdgcn_mfma_f32_16x16x32_bf16(xfr[3], wifr[3], acc1, 0,0,0);

        __syncthreads();          // all waves done reading old abuf (do_out t-2)
        consume(t - 1);           // speculative tagged loads -> validate -> abuf
        __syncthreads();          // abuf complete & visible to all waves

        // + a_{t-1} @ wrec^T
#pragma unroll
        for (int kt = 0; kt < 32; kt += 2) {
            short8 a0f = *(const short8*)&abuf[kt * 512 + lane * 8];
            short8 a1f = *(const short8*)&abuf[(kt + 1) * 512 + lane * 8];
            acc0 = __builtin_amdgcn_mfma_f32_16x16x32_bf16(a0f, wfr[kt],     acc0, 0,0,0);
            acc1 = __builtin_amdgcn_mfma_f32_16x16x32_bf16(a1f, wfr[kt + 1], acc1, 0,0,0);
        }

        // h update; stage a_t in aloc (wave-private region), publish immediately
#pragma unroll
        for (int r = 0; r < 4; ++r) {
            float z  = acc0[r] + acc1[r];
            float hv = (1.0f - ALPHA) * hreg[r] + ALPHA * z;
            hreg[r] = hv;
            aloc[off_l + (4 * q + r) * 8] = f2b(gv * tanh_fast(hv + bv));
        }
        publish(t);               // fire-and-forget tagged stores

        // off critical path: x prefetch + out for step t-1
        if (t < T_DIM - 1) {
#pragma unroll
            for (int kt = 0; kt < 4; ++kt)
                xfr[kt] = ld8f(&x[((size_t)(b0 + n) * T_DIM + t) * I_DIM + kt * 32 + q * 8]);
        }
        do_out(t - 1);
    }

    // epilogue: out[:, 511, :] from a_511
    __syncthreads();
    consume(T_DIM - 1);
    __syncthreads();
    do_out(T_DIM - 1);
}

extern "C" void kernel_launch(void* const* d_in, const int* in_sizes, int n_in,
                              void* d_out, int out_size, void* d_ws, size_t ws_size,
                              hipStream_t stream) {
    const float* x    = (const float*)d_in[0];
    const float* wi   = (const float*)d_in[1];
    const float* wrec = (const float*)d_in[2];
    const float* wout = (const float*)d_in[3];
    const float* bb   = (const float*)d_in[4];
    const float* gg   = (const float*)d_in[5];
    const float* h0   = (const float*)d_in[6];
    float* outp = (float*)d_out;

    // 2 parities x 4 groups x 64 KB tagged records = 512 KB. No init needed:
    // 0xAA poison reads as tag 0xAAAA which never matches a step tag -> retried.
    unsigned long long* aG = (unsigned long long*)d_ws;

    hipLaunchKernelGGL(rnn_kernel, dim3(NWG), dim3(256), 0, stream,
                       x, wi, wrec, wout, bb, gg, h0, outp, aG);
}

// Round 9
// 2279.624 us; speedup vs baseline: 1.0279x; 1.0279x over previous
//
#include <hip/hip_runtime.h>

#define H 1024
#define I_DIM 128
#define O_DIM 128
#define T_DIM 512
#define ALPHA 0.2f
#define NWG 64          // 4 batch-groups x 16 j-slices
#define GSZ 16          // WGs per batch-group

typedef short short8 __attribute__((ext_vector_type(8)));
typedef float f32x4 __attribute__((ext_vector_type(4)));
typedef unsigned long long ull_alias __attribute__((may_alias));

__device__ __forceinline__ unsigned short f2b(float f) {
    union { float f; unsigned u; } x; x.f = f;
    unsigned u = x.u;
    return (unsigned short)((u + 0x7FFFu + ((u >> 16) & 1u)) >> 16);
}
__device__ __forceinline__ float tanh_fast(float x) {
    float e = __expf(2.0f * x);
    return 1.0f - 2.0f * __builtin_amdgcn_rcpf(e + 1.0f);
}
// 8 contiguous f32 -> bf16 fragment (RNE)
__device__ __forceinline__ short8 ld8f(const float* __restrict__ p) {
    const float4 a = *(const float4*)p;
    const float4 b = *(const float4*)(p + 4);
    short8 r;
    r[0]=(short)f2b(a.x); r[1]=(short)f2b(a.y); r[2]=(short)f2b(a.z); r[3]=(short)f2b(a.w);
    r[4]=(short)f2b(b.x); r[5]=(short)f2b(b.y); r[6]=(short)f2b(b.z); r[7]=(short)f2b(b.w);
    return r;
}

// Embedded-tag protocol: each logical 8 B of packed-A data (4 bf16) becomes a
// PAIR of self-verifying 8 B slots:
//   slot0 = d0 | d1<<16 | d2<<32 | tag<<48
//   slot1 = d3 |       ...       | tag<<48      (tag = step & 0xFFFF)
// Relaxed agent-scope atomics only (LLC-coherent); NO drains, NO tag array,
// NO acquire/release, NO cache maintenance. Consumers load all slots
// speculatively, validate tags in ONE round, retry only stale units.
// WAR safety on the 2-parity ring without drains: producer P issues t+2 stores
// only after validating all of t+1; any wave published t+1 only after fully
// consuming (validating) t, which requires t's data to have ARRIVED at LLC.
// So P's t-stores are globally visible before its t+2 stores are issued.
// 8 B-aligned dwordx2 stores are single-copy atomic -> a slot is never torn;
// any old/new mix across slots is caught by the per-slot tag check.
// Unit index u in [0,4096): producer (ji,w,lane): u = ji*256 + w*64 + lane.
// Consumer wave w, i in [0,16): u = w*1024 + i*64 + lane = abuf u64 index.
__global__ __launch_bounds__(256, 1) void rnn_kernel(
    const float* __restrict__ x, const float* __restrict__ wi,
    const float* __restrict__ wrec, const float* __restrict__ wout,
    const float* __restrict__ bb, const float* __restrict__ gg,
    const float* __restrict__ h0p, float* __restrict__ out,
    unsigned long long* __restrict__ aG)
{
    __shared__ unsigned short abuf[32 * 512];   // 32 KB: group's full a_{t-1}
    __shared__ unsigned short aloc[1024];       // 2 KB: own a_t slice, packed
    __shared__ float opart[4 * 128];            // 2 KB: out k-partials

    const int tid  = threadIdx.x;
    const int w    = tid >> 6, lane = tid & 63;
    const int n    = lane & 15, q = lane >> 4;
    const int grp  = blockIdx.x & 3;
    const int ji   = blockIdx.x >> 2;
    const int j0   = ji * 64;
    const int j    = j0 + w * 16 + n;           // this lane's owned h row
    const int b0   = grp * 16;

    // ---- register-resident weights (f32 -> bf16, once) ----
    short8 wfr[32];                              // wrec B-frags: B[k][j] = wrec[j][k]
#pragma unroll
    for (int kt = 0; kt < 32; ++kt)
        wfr[kt] = ld8f(&wrec[(size_t)j * H + kt * 32 + q * 8]);

    short8 wifr[4];                              // wi B-frags: B[k][j] = wi[k][j]
#pragma unroll
    for (int kt = 0; kt < 4; ++kt) {
        short8 v;
#pragma unroll
        for (int i = 0; i < 8; ++i)
            v[i] = (short)f2b(wi[(size_t)(kt * 32 + q * 8 + i) * H + j]);
        wifr[kt] = v;
    }
    short8 wofr[8];                              // wout B-frags, cols ji*8..+8, zero-pad n>=8
#pragma unroll
    for (int kk = 0; kk < 8; ++kk) {
        short8 v;
        const int kb = (w * 8 + kk) * 32 + q * 8;
#pragma unroll
        for (int i = 0; i < 8; ++i)
            v[i] = (n < 8) ? (short)f2b(wout[(size_t)(kb + i) * O_DIM + ji * 8 + n]) : (short)0;
        wofr[kk] = v;
    }

    const float gv = gg[j], bv = bb[j], h00 = h0p[j];
    float hreg[4];
#pragma unroll
    for (int r = 0; r < 4; ++r) hreg[r] = h00;

    const int kl    = w * 16 + n;                // local k in [0,64)
    const int off_l = (kl >> 5) * 512 + ((kl & 31) >> 3) * 128 + (kl & 7);
    const int upub  = ji * 256 + w * 64 + lane;  // this lane's unit index

    // publish: read own 8 B from aloc, split into 2 tagged slots, fire & forget
    auto publish = [&](int t) {
        asm volatile("" ::: "memory");
        unsigned long long v = *(const ull_alias*)&aloc[w * 256 + lane * 4];
        const unsigned long long tg = (unsigned long long)(t & 0xFFFF) << 48;
        unsigned long long s0 = (v & 0x0000FFFFFFFFFFFFull) | tg;
        unsigned long long s1 = ((v >> 48) & 0xFFFFull) | tg;
        unsigned long long* dst =
            aG + (size_t)((t & 1) * 4 + grp) * 8192 + (size_t)upub * 2;
        __hip_atomic_store(dst + 0, s0, __ATOMIC_RELAXED, __HIP_MEMORY_SCOPE_AGENT);
        __hip_atomic_store(dst + 1, s1, __ATOMIC_RELAXED, __HIP_MEMORY_SCOPE_AGENT);
    };

    // consume: 32 speculative loads in ONE batch, single validation round,
    // per-lane exec-masked retry of only the stale units, then ds_write abuf.
    auto consume = [&](int tv) {
        const unsigned long long want = (unsigned long long)(tv & 0xFFFF);
        const unsigned long long* src = aG + (size_t)((tv & 1) * 4 + grp) * 8192;
        unsigned long long s0[16], s1[16];
#pragma unroll
        for (int i = 0; i < 16; ++i) {
            const unsigned long long* p =
                src + (size_t)(w * 1024 + i * 64 + lane) * 2;
            s0[i] = __hip_atomic_load(p + 0, __ATOMIC_RELAXED, __HIP_MEMORY_SCOPE_AGENT);
            s1[i] = __hip_atomic_load(p + 1, __ATOMIC_RELAXED, __HIP_MEMORY_SCOPE_AGENT);
        }
        for (;;) {
            unsigned bad = 0;
#pragma unroll
            for (int i = 0; i < 16; ++i)
                if (((s0[i] >> 48) != want) || ((s1[i] >> 48) != want)) bad |= 1u << i;
            if (__all(bad == 0)) break;
#pragma unroll
            for (int i = 0; i < 16; ++i)
                if (bad & (1u << i)) {
                    const unsigned long long* p =
                        src + (size_t)(w * 1024 + i * 64 + lane) * 2;
                    s0[i] = __hip_atomic_load(p + 0, __ATOMIC_RELAXED, __HIP_MEMORY_SCOPE_AGENT);
                    s1[i] = __hip_atomic_load(p + 1, __ATOMIC_RELAXED, __HIP_MEMORY_SCOPE_AGENT);
                }
        }
        asm volatile("" ::: "memory");
        ull_alias* d64 = (ull_alias*)abuf;
#pragma unroll
        for (int i = 0; i < 16; ++i)
            d64[(size_t)w * 1024 + i * 64 + lane] =
                (s0[i] & 0x0000FFFFFFFFFFFFull) | ((s1[i] & 0xFFFFull) << 48);
    };

    // out[:, t, ji*8..+8) from abuf (full k=1024 chain)
    auto do_out = [&](int t) {
        f32x4 oa = {0.f, 0.f, 0.f, 0.f};
#pragma unroll
        for (int kk = 0; kk < 8; ++kk) {
            short8 af = *(const short8*)&abuf[(w * 8 + kk) * 512 + lane * 8];
            oa = __builtin_amdgcn_mfma_f32_16x16x32_bf16(af, wofr[kk], oa, 0, 0, 0);
        }
        if (n < 8) {
#pragma unroll
            for (int r = 0; r < 4; ++r) opart[w * 128 + (4 * q + r) * 8 + n] = oa[r];
        }
        __syncthreads();
        if (tid < 128) {
            float s = opart[tid] + opart[128 + tid] + opart[256 + tid] + opart[384 + tid];
            const int m = tid >> 3, c = tid & 7;
            out[((size_t)(b0 + m) * T_DIM + t) * O_DIM + ji * 8 + c] = s;
        }
    };

    // ---- init: stage + publish a0 = g*tanh(h0+b) (batch-broadcast) ----
    {
        unsigned short a0 = f2b(gv * tanh_fast(h00 + bv));
#pragma unroll
        for (int r = 0; r < 4; ++r) aloc[off_l + (4 * q + r) * 8] = a0;
        publish(0);
    }

    short8 xfr[4];                               // prefetch x[:,0,:]
#pragma unroll
    for (int kt = 0; kt < 4; ++kt)
        xfr[kt] = ld8f(&x[(size_t)(b0 + n) * T_DIM * I_DIM + kt * 32 + q * 8]);

    for (int t = 1; t < T_DIM; ++t) {
        // x@wi partials: register-only, overlaps stragglers
        f32x4 acc0 = {0.f,0.f,0.f,0.f}, acc1 = {0.f,0.f,0.f,0.f};
        acc0 = __builtin_amdgcn_mfma_f32_16x16x32_bf16(xfr[0], wifr[0], acc0, 0,0,0);
        acc1 = __builtin_amdgcn_mfma_f32_16x16x32_bf16(xfr[1], wifr[1], acc1, 0,0,0);
        acc0 = __builtin_amdgcn_mfma_f32_16x16x32_bf16(xfr[2], wifr[2], acc0, 0,0,0);
        acc1 = __builtin_amdgcn_mfma_f32_16x16x32_bf16(xfr[3], wifr[3], acc1, 0,0,0);

        __syncthreads();          // all waves done reading old abuf (do_out t-2)
        consume(t - 1);           // speculative tagged loads, 1 validation round
        __syncthreads();          // abuf complete & visible to all waves

        // + a_{t-1} @ wrec^T
#pragma unroll
        for (int kt = 0; kt < 32; kt += 2) {
            short8 a0f = *(const short8*)&abuf[kt * 512 + lane * 8];
            short8 a1f = *(const short8*)&abuf[(kt + 1) * 512 + lane * 8];
            acc0 = __builtin_amdgcn_mfma_f32_16x16x32_bf16(a0f, wfr[kt],     acc0, 0,0,0);
            acc1 = __builtin_amdgcn_mfma_f32_16x16x32_bf16(a1f, wfr[kt + 1], acc1, 0,0,0);
        }

        // h update; stage a_t in aloc (wave-private region), publish immediately
#pragma unroll
        for (int r = 0; r < 4; ++r) {
            float z  = acc0[r] + acc1[r];
            float hv = (1.0f - ALPHA) * hreg[r] + ALPHA * z;
            hreg[r] = hv;
            aloc[off_l + (4 * q + r) * 8] = f2b(gv * tanh_fast(hv + bv));
        }
        publish(t);               // fire-and-forget tagged stores (no drain)

        // off critical path: x prefetch + out for step t-1 (hides visibility)
        if (t < T_DIM - 1) {
#pragma unroll
            for (int kt = 0; kt < 4; ++kt)
                xfr[kt] = ld8f(&x[((size_t)(b0 + n) * T_DIM + t) * I_DIM + kt * 32 + q * 8]);
        }
        do_out(t - 1);
    }

    // epilogue: out[:, 511, :] from a_511
    __syncthreads();
    consume(T_DIM - 1);
    __syncthreads();
    do_out(T_DIM - 1);
}

extern "C" void kernel_launch(void* const* d_in, const int* in_sizes, int n_in,
                              void* d_out, int out_size, void* d_ws, size_t ws_size,
                              hipStream_t stream) {
    const float* x    = (const float*)d_in[0];
    const float* wi   = (const float*)d_in[1];
    const float* wrec = (const float*)d_in[2];
    const float* wout = (const float*)d_in[3];
    const float* bb   = (const float*)d_in[4];
    const float* gg   = (const float*)d_in[5];
    const float* h0   = (const float*)d_in[6];
    float* outp = (float*)d_out;

    // 2 parities x 4 groups x 64 KB tagged records = 512 KB. No init needed:
    // 0xAA poison reads as tag 0xAAAA which never matches any step tag (<512),
    // and the harness re-poisons d_ws before every timed launch.
    unsigned long long* aG = (unsigned long long*)d_ws;

    hipLaunchKernelGGL(rnn_kernel, dim3(NWG), dim3(256), 0, stream,
                       x, wi, wrec, wout, bb, gg, h0, outp, aG);
}